// Round 14
// baseline (146.694 us; speedup 1.0000x reference)
//
#include <hip/hip_runtime.h>
#include <math.h>

#define NLB 96          // L*B = 3*32
#define CC  256
#define PP  49
#define QQ  961
#define TEMP_INV 40.0f  // 1/0.025
#define BN_EPS 1e-5f

#define N1 (NLB*CC*PP)  // 1,204,224
#define N2 (NLB*CC*QQ)  // 23,617,536

typedef __attribute__((ext_vector_type(8))) short bf16x8;
typedef __attribute__((ext_vector_type(4))) float f32x4;
typedef __attribute__((ext_vector_type(8))) unsigned short ushort8;

__device__ inline unsigned short f2bf(float x) {  // RNE float->bf16
    unsigned int u = __float_as_uint(x);
    unsigned int r = (u + 0x7fffu + ((u >> 16) & 1u)) >> 16;
    return (unsigned short)r;
}

// async global->LDS, 4B per lane; LDS dest = uniform base + lane*4
__device__ __forceinline__ void gload_lds4(const float* g, float* l) {
    __builtin_amdgcn_global_load_lds(
        (const __attribute__((address_space(1))) void*)g,
        (__attribute__((address_space(3))) void*)l,
        4, 0, 0);
}

// ---------------- prep_z: zf -> f1T bf16 [lb][p(64)][c], inv1, zero mrow ----
__global__ __launch_bounds__(256) void prep_z(
    const float* __restrict__ zf, unsigned short* __restrict__ f1T,
    float* __restrict__ inv1_ws, float* __restrict__ mrow_ws)
{
    const int lb = blockIdx.x;
    if (threadIdx.x < PP) mrow_ws[lb * PP + threadIdx.x] = 0.f;

    const float* __restrict__ f1 = zf + (size_t)lb * CC * PP;
    const int p  = threadIdx.x >> 2;   // 0..63
    const int qu = threadIdx.x & 3;
    const int c0 = qu * 64;
    float ss = 0.f;
    ushort8* dst = (ushort8*)(f1T + ((size_t)lb * 64 + p) * CC + c0);
#pragma unroll
    for (int s = 0; s < 8; ++s) {
        unsigned short tmp[8];
#pragma unroll
        for (int j = 0; j < 8; ++j) {
            const float v = (p < PP) ? f1[(size_t)(c0 + s * 8 + j) * PP + p] : 0.f;
            ss = fmaf(v, v, ss);
            tmp[j] = f2bf(v);
        }
        dst[s] = *(ushort8*)tmp;
    }
    ss += __shfl_xor(ss, 1, 64);
    ss += __shfl_xor(ss, 2, 64);
    if (qu == 0) inv1_ws[lb * 64 + p] = (p < PP) ? 1.0f / fmaxf(sqrtf(ss), 1e-12f) : 0.f;
}

// ---------------- corr: MFMA GEMM with async global_load_lds staging --------
// grid (8 ng, 96 lb), 512 threads (8 waves). Per chunk (64 c): stage f2 rows
// [64][128q] f32 row-linear into LDS via global_load_lds (async, coalesced
// 256B/inst, 128 insts/block in flight), double-buffered, one barrier/chunk.
// Waves read column fragments from LDS (4-way bank conflict = 1.58x, hidden),
// convert to bf16 in-reg, MFMA. Strided-scalar direct reads plateaued at
// ~1.5 TB/s across r9-r13 regardless of ILP/TLP; async staging is the fix.
#define STAGE(BUF, KC)                                                         \
    {                                                                          \
        const int c0s = (KC) * 64 + wave * 8;                                  \
        _Pragma("unroll")                                                      \
        for (int r8 = 0; r8 < 8; ++r8) {                                       \
            _Pragma("unroll")                                                  \
            for (int h = 0; h < 2; ++h) {                                      \
                const int qi = ng * 128 + h * 64 + lane;                       \
                const int qc2 = qi < QQ ? qi : QQ - 1;                         \
                gload_lds4(f2 + (size_t)(c0s + r8) * QQ + qc2,                 \
                           &BUF[(wave * 8 + r8) * 128 + h * 64]);              \
            }                                                                  \
        }                                                                      \
    }

#define COMPS(BUF, KC)                                                         \
    {                                                                          \
        bf16x8 af[4][2];                                                       \
        _Pragma("unroll")                                                      \
        for (int mt = 0; mt < 4; ++mt)                                         \
            _Pragma("unroll")                                                  \
            for (int ks = 0; ks < 2; ++ks)                                     \
                af[mt][ks] = *(const bf16x8*)&f1L[(mt * 16 + l15) * 264 +      \
                                                  (KC) * 64 + ks * 32 + g4 * 8];\
        _Pragma("unroll")                                                      \
        for (int ks = 0; ks < 2; ++ks) {                                       \
            unsigned short us[8];                                              \
            _Pragma("unroll")                                                  \
            for (int j = 0; j < 8; ++j) {                                      \
                const float v = BUF[(ks * 32 + g4 * 8 + j) * 128 + wq + l15];  \
                ss2 = fmaf(v, v, ss2);                                         \
                us[j] = f2bf(v);                                               \
            }                                                                  \
            const bf16x8 bfr = *(const bf16x8*)us;                             \
            _Pragma("unroll")                                                  \
            for (int mt = 0; mt < 4; ++mt)                                     \
                acc[mt] = __builtin_amdgcn_mfma_f32_16x16x32_bf16(             \
                    af[mt][ks], bfr, acc[mt], 0, 0, 0);                        \
        }                                                                      \
    }

__global__ __launch_bounds__(512) void corr_mfma(
    const unsigned short* __restrict__ f1T, const float* __restrict__ xf,
    const float* __restrict__ inv1_ws,
    float* __restrict__ A_all, float* __restrict__ mcol_ws,
    float* __restrict__ mrow_ws)
{
    const int ng = blockIdx.x;           // 0..7, q0 = ng*128
    const int lb = blockIdx.y;
    const int tid  = threadIdx.x;
    const int lane = tid & 63;
    const int wave = tid >> 6;           // 0..7
    const int g4   = lane >> 4;
    const int l15  = lane & 15;
    const int wq   = wave * 16;

    const float* __restrict__ f2 = xf + (size_t)lb * CC * QQ;

    __shared__ __align__(16) unsigned short f1L[64 * 264];   // 33.8 KB
    __shared__ float inv1L[64];
    __shared__ __align__(16) float bufA[64 * 128];           // 32 KB
    __shared__ __align__(16) float bufB[64 * 128];           // 32 KB

    STAGE(bufA, 0)                       // async; drains at first barrier
    for (int i = tid; i < 64 * 32; i += 512) {
        const int row = i >> 5, seg = i & 31;
        *(ushort8*)&f1L[row * 264 + seg * 8] =
            *(const ushort8*)&f1T[((size_t)lb * 64 + row) * CC + seg * 8];
    }
    if (tid < 64) inv1L[tid] = inv1_ws[lb * 64 + tid];
    __syncthreads();

    const int qg = ng * 128 + wq + l15;  // this wave's q column
    const bool qv = (qg < QQ);

    f32x4 acc[4];
#pragma unroll
    for (int mt = 0; mt < 4; ++mt) acc[mt] = (f32x4)0.f;
    float ss2 = 0.f;

    STAGE(bufB, 1)
    COMPS(bufA, 0)
    __syncthreads();
    STAGE(bufA, 2)
    COMPS(bufB, 1)
    __syncthreads();
    STAGE(bufB, 3)
    COMPS(bufA, 2)
    __syncthreads();
    COMPS(bufB, 3)

    // epilogue: inv2 from this column's sumsq (reduce over the 4 g4 groups)
    float ssf = ss2;
    ssf += __shfl_xor(ssf, 16, 64);
    ssf += __shfl_xor(ssf, 32, 64);
    const float iv2 = 1.0f / fmaxf(sqrtf(ssf), 1e-12f);

    float* __restrict__ Aout = A_all + (size_t)lb * PP * QQ;
    float vv[16];
    float cs = 0.f;
#pragma unroll
    for (int mt = 0; mt < 4; ++mt)
#pragma unroll
        for (int r = 0; r < 4; ++r) {
            const int p = mt * 16 + g4 * 4 + r;
            // zero invalid-q lanes: their staged data is clamp-garbage and
            // they feed the mrow cross-lane sums below
            const float v = qv ? acc[mt][r] * inv1L[p] * iv2 : 0.f;
            vv[mt * 4 + r] = v;
            cs += v;
            if (p < PP && qv) Aout[(size_t)p * QQ + qg] = v;
        }
    cs += __shfl_xor(cs, 16, 64);
    cs += __shfl_xor(cs, 32, 64);
    if ((lane < 16) && qv) mcol_ws[lb * QQ + qg] = cs;
#pragma unroll
    for (int mt = 0; mt < 4; ++mt)
#pragma unroll
        for (int r = 0; r < 4; ++r) {
            const int p = mt * 16 + g4 * 4 + r;
            float s = vv[mt * 4 + r];
            s += __shfl_xor(s, 1, 64);
            s += __shfl_xor(s, 2, 64);
            s += __shfl_xor(s, 4, 64);
            s += __shfl_xor(s, 8, 64);
            if (((lane & 15) == 0) && p < PP) atomicAdd(&mrow_ws[lb * PP + p], s);
        }
}

// ---------------- attn: MLPs + softmaxes ------------------------------------
__global__ __launch_bounds__(512) void attn_kernel(
    const float* __restrict__ A_all,
    const float* __restrict__ mcol_ws, const float* __restrict__ mrow_ws,
    const float* __restrict__ W1, const float* __restrict__ b1,
    const float* __restrict__ g1, const float* __restrict__ bb1,
    const float* __restrict__ rm1, const float* __restrict__ rv1,
    const float* __restrict__ W2, const float* __restrict__ b2,
    const float* __restrict__ W3, const float* __restrict__ b3,
    const float* __restrict__ g3, const float* __restrict__ bb3,
    const float* __restrict__ rm3, const float* __restrict__ rv3,
    const float* __restrict__ W4, const float* __restrict__ b4,
    float* __restrict__ att1_ws, float* __restrict__ att2_ws)
{
    const int lb = blockIdx.x;
    const float* __restrict__ A = A_all + (size_t)lb * PP * QQ;
    const int tid  = threadIdx.x;
    const int lane = tid & 63;
    const int wv   = tid >> 6;

    __shared__ float mcolL[QQ];
    __shared__ float mrowL[PP];
    __shared__ float taL[31], tbL[7];
    __shared__ float t2aL[QQ], t2bL[PP];
    __shared__ float s2sL[QQ];
    __shared__ float s1L[PP];
    __shared__ float redM[8], redS[8];

    for (int q = tid; q < QQ; q += 512) mcolL[q] = mcol_ws[lb * QQ + q] * (1.0f / PP);
    if (tid < PP) mrowL[tid] = mrow_ws[lb * PP + tid] * (1.0f / QQ);
    __syncthreads();

    if (tid < 31 * 16) {
        const int k = tid >> 4, sub = tid & 15;
        float s = 0.f;
        for (int q = sub; q < QQ; q += 16) s = fmaf(mcolL[q], W1[k * QQ + q], s);
        s += __shfl_xor(s, 1, 64); s += __shfl_xor(s, 2, 64);
        s += __shfl_xor(s, 4, 64); s += __shfl_xor(s, 8, 64);
        if (sub == 0) {
            float t = s + b1[k];
            t = (t - rm1[k]) * rsqrtf(rv1[k] + BN_EPS) * g1[k] + bb1[k];
            taL[k] = fmaxf(t, 0.f);
        }
    }
    if (tid < 7 * 8) {
        const int k = tid >> 3, sub = tid & 7;
        float s = 0.f;
        for (int p = sub; p < PP; p += 8) s = fmaf(mrowL[p], W3[k * PP + p], s);
        s += __shfl_xor(s, 1, 64); s += __shfl_xor(s, 2, 64); s += __shfl_xor(s, 4, 64);
        if (sub == 0) {
            float t = s + b3[k];
            t = (t - rm3[k]) * rsqrtf(rv3[k] + BN_EPS) * g3[k] + bb3[k];
            tbL[k] = fmaxf(t, 0.f);
        }
    }
    __syncthreads();

    for (int q = tid; q < QQ; q += 512) {
        float s = b2[q];
#pragma unroll
        for (int k = 0; k < 31; ++k) s = fmaf(taL[k], W2[q * 31 + k], s);
        t2aL[q] = s;
    }
    if (tid < PP) {
        float s = b4[tid];
#pragma unroll
        for (int k = 0; k < 7; ++k) s = fmaf(tbL[k], W4[tid * 7 + k], s);
        t2bL[tid] = s;
    }
    __syncthreads();

    for (int q = tid; q < QQ; q += 512) {
        float s = 0.f;
#pragma unroll
        for (int p = 0; p < PP; ++p) s = fmaf(A[(size_t)p * QQ + q], t2bL[p], s);
        s2sL[q] = s * (1.0f / PP) * TEMP_INV;
    }
    for (int p = wv; p < PP; p += 8) {
        float s = 0.f;
        for (int q = lane; q < QQ; q += 64) s = fmaf(A[(size_t)p * QQ + q], t2aL[q], s);
        for (int off = 32; off > 0; off >>= 1) s += __shfl_xor(s, off, 64);
        if (lane == 0) s1L[p] = s * (1.0f / QQ) * TEMP_INV;
    }
    __syncthreads();

    if (wv == 0) {
        const float v = (lane < PP) ? s1L[lane] : -3.4e38f;
        float m = v;
        for (int off = 32; off > 0; off >>= 1) m = fmaxf(m, __shfl_xor(m, off, 64));
        const float e = (lane < PP) ? expf(v - m) : 0.f;
        float sum = e;
        for (int off = 32; off > 0; off >>= 1) sum += __shfl_xor(sum, off, 64);
        if (lane < PP) att1_ws[lb * PP + lane] = e / sum + 1.0f;
    }

    float lm = -3.4e38f;
    for (int q = tid; q < QQ; q += 512) lm = fmaxf(lm, s2sL[q]);
    for (int off = 32; off > 0; off >>= 1) lm = fmaxf(lm, __shfl_xor(lm, off, 64));
    if (lane == 0) redM[wv] = lm;
    __syncthreads();
    float gm = redM[0];
#pragma unroll
    for (int i = 1; i < 8; ++i) gm = fmaxf(gm, redM[i]);
    float ls = 0.f;
    for (int q = tid; q < QQ; q += 512) ls += expf(s2sL[q] - gm);
    for (int off = 32; off > 0; off >>= 1) ls += __shfl_xor(ls, off, 64);
    if (lane == 0) redS[wv] = ls;
    __syncthreads();
    float tot = 0.f;
#pragma unroll
    for (int i = 0; i < 8; ++i) tot += redS[i];
    const float rinv = 1.0f / tot;
    for (int q = tid; q < QQ; q += 512)
        att2_ws[lb * QQ + q] = expf(s2sL[q] - gm) * rinv + 1.0f;
}

// -------- scale: out = in * att[lb, inner], float4-vectorized ---------------
template <int INNER>
__global__ __launch_bounds__(256) void scale_kernel(
    const float* __restrict__ in, const float* __restrict__ att,
    float* __restrict__ out, int n4)
{
    const int i = blockIdx.x * 256 + threadIdx.x;
    if (i >= n4) return;
    const float4 v = reinterpret_cast<const float4*>(in)[i];
    const float* vv = reinterpret_cast<const float*>(&v);
    float4 o;
    float* ov = reinterpret_cast<float*>(&o);
    const int g = i * 4;
#pragma unroll
    for (int j = 0; j < 4; ++j) {
        const int gg = g + j;
        const int lb = gg / (CC * INNER);
        const int x  = gg % INNER;
        ov[j] = vv[j] * att[lb * INNER + x];
    }
    reinterpret_cast<float4*>(out)[i] = o;
}

extern "C" void kernel_launch(void* const* d_in, const int* in_sizes, int n_in,
                              void* d_out, int out_size, void* d_ws, size_t ws_size,
                              hipStream_t stream)
{
    const float* zf  = (const float*)d_in[0];
    const float* xf  = (const float*)d_in[1];
    const float* W1  = (const float*)d_in[2];
    const float* b1  = (const float*)d_in[3];
    const float* g1  = (const float*)d_in[4];
    const float* bb1 = (const float*)d_in[5];
    const float* rm1 = (const float*)d_in[6];
    const float* rv1 = (const float*)d_in[7];
    const float* W2  = (const float*)d_in[8];
    const float* b2  = (const float*)d_in[9];
    const float* W3  = (const float*)d_in[10];
    const float* b3  = (const float*)d_in[11];
    const float* g3  = (const float*)d_in[12];
    const float* bb3 = (const float*)d_in[13];
    const float* rm3 = (const float*)d_in[14];
    const float* rv3 = (const float*)d_in[15];
    const float* W4  = (const float*)d_in[16];
    const float* b4  = (const float*)d_in[17];

    char* wsb = (char*)d_ws;
    unsigned short* f1T = (unsigned short*)wsb;                       // 96*64*256 us
    float* fbase = (float*)(f1T + (size_t)NLB * 64 * CC);
    float* A     = fbase;                                             // 96*49*961
    float* att1  = A + (size_t)NLB * PP * QQ;
    float* att2  = att1 + (size_t)NLB * PP;
    float* mcol  = att2 + (size_t)NLB * QQ;
    float* mrow  = mcol + (size_t)NLB * QQ;
    float* inv1  = mrow + (size_t)NLB * PP;                           // 96*64

    float* out1 = (float*)d_out;
    float* out2 = out1 + N1;

    prep_z<<<NLB, 256, 0, stream>>>(zf, f1T, inv1, mrow);

    dim3 gcorr(8, NLB);
    corr_mfma<<<gcorr, 512, 0, stream>>>(f1T, xf, inv1, A, mcol, mrow);

    attn_kernel<<<NLB, 512, 0, stream>>>(A, mcol, mrow,
        W1, b1, g1, bb1, rm1, rv1, W2, b2,
        W3, b3, g3, bb3, rm3, rv3, W4, b4,
        att1, att2);

    const int n4_1 = N1 / 4;
    const int n4_2 = N2 / 4;
    scale_kernel<PP><<<(n4_1 + 255) / 256, 256, 0, stream>>>(zf, att1, out1, n4_1);
    scale_kernel<QQ><<<(n4_2 + 255) / 256, 256, 0, stream>>>(xf, att2, out2, n4_2);
}

// Round 15
// 127.499 us; speedup vs baseline: 1.1506x; 1.1506x over previous
//
#include <hip/hip_runtime.h>
#include <math.h>

#define NLB 96          // L*B = 3*32
#define CC  256
#define PP  49
#define QQ  961
#define TEMP_INV 40.0f  // 1/0.025
#define BN_EPS 1e-5f

#define N1 (NLB*CC*PP)  // 1,204,224
#define N2 (NLB*CC*QQ)  // 23,617,536

typedef __attribute__((ext_vector_type(8))) short bf16x8;
typedef __attribute__((ext_vector_type(4))) float f32x4;
typedef __attribute__((ext_vector_type(8))) unsigned short ushort8;

__device__ inline unsigned short f2bf(float x) {  // RNE float->bf16
    unsigned int u = __float_as_uint(x);
    unsigned int r = (u + 0x7fffu + ((u >> 16) & 1u)) >> 16;
    return (unsigned short)r;
}

// async global->LDS, 4B per lane; LDS dest = uniform base + lane*4
__device__ __forceinline__ void gload_lds4(const float* g, float* l) {
    __builtin_amdgcn_global_load_lds(
        (const __attribute__((address_space(1))) void*)g,
        (__attribute__((address_space(3))) void*)l,
        4, 0, 0);
}

// ---------------- prep_z: zf -> f1T bf16 [lb][p(64)][c], inv1, zero mrow ----
__global__ __launch_bounds__(256) void prep_z(
    const float* __restrict__ zf, unsigned short* __restrict__ f1T,
    float* __restrict__ inv1_ws, float* __restrict__ mrow_ws)
{
    const int lb = blockIdx.x;
    if (threadIdx.x < PP) mrow_ws[lb * PP + threadIdx.x] = 0.f;

    const float* __restrict__ f1 = zf + (size_t)lb * CC * PP;
    const int p  = threadIdx.x >> 2;   // 0..63
    const int qu = threadIdx.x & 3;
    const int c0 = qu * 64;
    float ss = 0.f;
    ushort8* dst = (ushort8*)(f1T + ((size_t)lb * 64 + p) * CC + c0);
#pragma unroll
    for (int s = 0; s < 8; ++s) {
        unsigned short tmp[8];
#pragma unroll
        for (int j = 0; j < 8; ++j) {
            const float v = (p < PP) ? f1[(size_t)(c0 + s * 8 + j) * PP + p] : 0.f;
            ss = fmaf(v, v, ss);
            tmp[j] = f2bf(v);
        }
        dst[s] = *(ushort8*)tmp;
    }
    ss += __shfl_xor(ss, 1, 64);
    ss += __shfl_xor(ss, 2, 64);
    if (qu == 0) inv1_ws[lb * 64 + p] = (p < PP) ? 1.0f / fmaxf(sqrtf(ss), 1e-12f) : 0.f;
}

// ---------------- corr: MFMA GEMM, 256-q tiles, 1KB-row async staging -------
// grid (4 ng, 96 lb), 512 threads (8 waves). Chunk = 32 c-rows x 256 q f32
// (33KB, single buffer; 67.6KB LDS total -> 2 blocks/CU). Each row staged as
// 4 consecutive gload_lds dword insts = 1KB contiguous (vs 512B segments in
// r9-r14, all of which plateaued ~70us). Epilogue: mrow reduced in LDS, 49
// global atomics/block (was 512).
#define STAGE(K)                                                               \
    {                                                                          \
        const int c0s = (K) * 32 + wave * 4;                                   \
        _Pragma("unroll")                                                      \
        for (int r = 0; r < 4; ++r) {                                          \
            _Pragma("unroll")                                                  \
            for (int i = 0; i < 4; ++i) {                                      \
                const int qcol = q0 + i * 64 + lane;                           \
                const int qc2 = qcol < QQ ? qcol : QQ - 1;                     \
                gload_lds4(f2 + (size_t)(c0s + r) * QQ + qc2,                  \
                           &buf[(wave * 4 + r) * 260 + i * 64]);               \
            }                                                                  \
        }                                                                      \
    }

#define COMPS(K)                                                               \
    {                                                                          \
        bf16x8 af[4];                                                          \
        _Pragma("unroll")                                                      \
        for (int mt = 0; mt < 4; ++mt)                                         \
            af[mt] = *(const bf16x8*)&f1L[(mt * 16 + l15) * 264 +              \
                                          (K) * 32 + g4 * 8];                  \
        _Pragma("unroll")                                                      \
        for (int i = 0; i < 2; ++i) {                                          \
            const int qloc = (wave + 8 * i) * 16 + l15;                        \
            unsigned short us[8];                                              \
            _Pragma("unroll")                                                  \
            for (int j = 0; j < 8; ++j) {                                      \
                const float v = buf[(g4 * 8 + j) * 260 + qloc];                \
                ss2[i] = fmaf(v, v, ss2[i]);                                   \
                us[j] = f2bf(v);                                               \
            }                                                                  \
            const bf16x8 bfr = *(const bf16x8*)us;                             \
            _Pragma("unroll")                                                  \
            for (int mt = 0; mt < 4; ++mt)                                     \
                acc[i][mt] = __builtin_amdgcn_mfma_f32_16x16x32_bf16(          \
                    af[mt], bfr, acc[i][mt], 0, 0, 0);                         \
        }                                                                      \
    }

__global__ __launch_bounds__(512) void corr_mfma(
    const unsigned short* __restrict__ f1T, const float* __restrict__ xf,
    const float* __restrict__ inv1_ws,
    float* __restrict__ A_all, float* __restrict__ mcol_ws,
    float* __restrict__ mrow_ws)
{
    const int ng = blockIdx.x;           // 0..3, q0 = ng*256
    const int lb = blockIdx.y;
    const int tid  = threadIdx.x;
    const int lane = tid & 63;
    const int wave = tid >> 6;           // 0..7
    const int g4   = lane >> 4;
    const int l15  = lane & 15;
    const int q0   = ng * 256;

    const float* __restrict__ f2 = xf + (size_t)lb * CC * QQ;

    __shared__ __align__(16) unsigned short f1L[64 * 264];   // 33.8 KB
    __shared__ float inv1L[64];
    __shared__ float mrowL[64];
    __shared__ __align__(16) float buf[32 * 260];            // 33.3 KB

    if (tid < 64) { inv1L[tid] = inv1_ws[lb * 64 + tid]; mrowL[tid] = 0.f; }
    STAGE(0)                              // async; drains at first barrier
    for (int i = tid; i < 64 * 32; i += 512) {
        const int row = i >> 5, seg = i & 31;
        *(ushort8*)&f1L[row * 264 + seg * 8] =
            *(const ushort8*)&f1T[((size_t)lb * 64 + row) * CC + seg * 8];
    }
    __syncthreads();

    f32x4 acc[2][4];
#pragma unroll
    for (int i = 0; i < 2; ++i)
#pragma unroll
        for (int mt = 0; mt < 4; ++mt) acc[i][mt] = (f32x4)0.f;
    float ss2[2] = {0.f, 0.f};

#pragma unroll
    for (int k = 0; k < 8; ++k) {
        COMPS(k)
        __syncthreads();                 // buf consumed
        if (k < 7) {
            STAGE(k + 1)
            __syncthreads();             // buf refilled (drains gload queue)
        }
    }

    float* __restrict__ Aout = A_all + (size_t)lb * PP * QQ;
#pragma unroll
    for (int i = 0; i < 2; ++i) {
        const int qg = q0 + (wave + 8 * i) * 16 + l15;
        const bool qv = (qg < QQ);
        float ssf = ss2[i];
        ssf += __shfl_xor(ssf, 16, 64);
        ssf += __shfl_xor(ssf, 32, 64);
        const float iv2 = 1.0f / fmaxf(sqrtf(ssf), 1e-12f);

        float vv[16];
        float cs = 0.f;
#pragma unroll
        for (int mt = 0; mt < 4; ++mt)
#pragma unroll
            for (int r = 0; r < 4; ++r) {
                const int p = mt * 16 + g4 * 4 + r;
                const float v = qv ? acc[i][mt][r] * inv1L[p] * iv2 : 0.f;
                vv[mt * 4 + r] = v;
                cs += v;
                if (p < PP && qv) Aout[(size_t)p * QQ + qg] = v;
            }
        cs += __shfl_xor(cs, 16, 64);
        cs += __shfl_xor(cs, 32, 64);
        if ((lane < 16) && qv) mcol_ws[lb * QQ + qg] = cs;
#pragma unroll
        for (int mt = 0; mt < 4; ++mt)
#pragma unroll
            for (int r = 0; r < 4; ++r) {
                const int p = mt * 16 + g4 * 4 + r;
                float s = vv[mt * 4 + r];
                s += __shfl_xor(s, 1, 64);
                s += __shfl_xor(s, 2, 64);
                s += __shfl_xor(s, 4, 64);
                s += __shfl_xor(s, 8, 64);
                if (((lane & 15) == 0) && p < PP) atomicAdd(&mrowL[p], s);
            }
    }
    __syncthreads();
    if (tid < PP) atomicAdd(&mrow_ws[lb * PP + tid], mrowL[tid]);
}

// ---------------- attn: MLPs + softmaxes ------------------------------------
__global__ __launch_bounds__(512) void attn_kernel(
    const float* __restrict__ A_all,
    const float* __restrict__ mcol_ws, const float* __restrict__ mrow_ws,
    const float* __restrict__ W1, const float* __restrict__ b1,
    const float* __restrict__ g1, const float* __restrict__ bb1,
    const float* __restrict__ rm1, const float* __restrict__ rv1,
    const float* __restrict__ W2, const float* __restrict__ b2,
    const float* __restrict__ W3, const float* __restrict__ b3,
    const float* __restrict__ g3, const float* __restrict__ bb3,
    const float* __restrict__ rm3, const float* __restrict__ rv3,
    const float* __restrict__ W4, const float* __restrict__ b4,
    float* __restrict__ att1_ws, float* __restrict__ att2_ws)
{
    const int lb = blockIdx.x;
    const float* __restrict__ A = A_all + (size_t)lb * PP * QQ;
    const int tid  = threadIdx.x;
    const int lane = tid & 63;
    const int wv   = tid >> 6;

    __shared__ float mcolL[QQ];
    __shared__ float mrowL[PP];
    __shared__ float taL[31], tbL[7];
    __shared__ float t2aL[QQ], t2bL[PP];
    __shared__ float s2sL[QQ];
    __shared__ float s1L[PP];
    __shared__ float redM[8], redS[8];

    for (int q = tid; q < QQ; q += 512) mcolL[q] = mcol_ws[lb * QQ + q] * (1.0f / PP);
    if (tid < PP) mrowL[tid] = mrow_ws[lb * PP + tid] * (1.0f / QQ);
    __syncthreads();

    if (tid < 31 * 16) {
        const int k = tid >> 4, sub = tid & 15;
        float s = 0.f;
        for (int q = sub; q < QQ; q += 16) s = fmaf(mcolL[q], W1[k * QQ + q], s);
        s += __shfl_xor(s, 1, 64); s += __shfl_xor(s, 2, 64);
        s += __shfl_xor(s, 4, 64); s += __shfl_xor(s, 8, 64);
        if (sub == 0) {
            float t = s + b1[k];
            t = (t - rm1[k]) * rsqrtf(rv1[k] + BN_EPS) * g1[k] + bb1[k];
            taL[k] = fmaxf(t, 0.f);
        }
    }
    if (tid < 7 * 8) {
        const int k = tid >> 3, sub = tid & 7;
        float s = 0.f;
        for (int p = sub; p < PP; p += 8) s = fmaf(mrowL[p], W3[k * PP + p], s);
        s += __shfl_xor(s, 1, 64); s += __shfl_xor(s, 2, 64); s += __shfl_xor(s, 4, 64);
        if (sub == 0) {
            float t = s + b3[k];
            t = (t - rm3[k]) * rsqrtf(rv3[k] + BN_EPS) * g3[k] + bb3[k];
            tbL[k] = fmaxf(t, 0.f);
        }
    }
    __syncthreads();

    for (int q = tid; q < QQ; q += 512) {
        float s = b2[q];
#pragma unroll
        for (int k = 0; k < 31; ++k) s = fmaf(taL[k], W2[q * 31 + k], s);
        t2aL[q] = s;
    }
    if (tid < PP) {
        float s = b4[tid];
#pragma unroll
        for (int k = 0; k < 7; ++k) s = fmaf(tbL[k], W4[tid * 7 + k], s);
        t2bL[tid] = s;
    }
    __syncthreads();

    for (int q = tid; q < QQ; q += 512) {
        float s = 0.f;
#pragma unroll
        for (int p = 0; p < PP; ++p) s = fmaf(A[(size_t)p * QQ + q], t2bL[p], s);
        s2sL[q] = s * (1.0f / PP) * TEMP_INV;
    }
    for (int p = wv; p < PP; p += 8) {
        float s = 0.f;
        for (int q = lane; q < QQ; q += 64) s = fmaf(A[(size_t)p * QQ + q], t2aL[q], s);
        for (int off = 32; off > 0; off >>= 1) s += __shfl_xor(s, off, 64);
        if (lane == 0) s1L[p] = s * (1.0f / QQ) * TEMP_INV;
    }
    __syncthreads();

    if (wv == 0) {
        const float v = (lane < PP) ? s1L[lane] : -3.4e38f;
        float m = v;
        for (int off = 32; off > 0; off >>= 1) m = fmaxf(m, __shfl_xor(m, off, 64));
        const float e = (lane < PP) ? expf(v - m) : 0.f;
        float sum = e;
        for (int off = 32; off > 0; off >>= 1) sum += __shfl_xor(sum, off, 64);
        if (lane < PP) att1_ws[lb * PP + lane] = e / sum + 1.0f;
    }

    float lm = -3.4e38f;
    for (int q = tid; q < QQ; q += 512) lm = fmaxf(lm, s2sL[q]);
    for (int off = 32; off > 0; off >>= 1) lm = fmaxf(lm, __shfl_xor(lm, off, 64));
    if (lane == 0) redM[wv] = lm;
    __syncthreads();
    float gm = redM[0];
#pragma unroll
    for (int i = 1; i < 8; ++i) gm = fmaxf(gm, redM[i]);
    float ls = 0.f;
    for (int q = tid; q < QQ; q += 512) ls += expf(s2sL[q] - gm);
    for (int off = 32; off > 0; off >>= 1) ls += __shfl_xor(ls, off, 64);
    if (lane == 0) redS[wv] = ls;
    __syncthreads();
    float tot = 0.f;
#pragma unroll
    for (int i = 0; i < 8; ++i) tot += redS[i];
    const float rinv = 1.0f / tot;
    for (int q = tid; q < QQ; q += 512)
        att2_ws[lb * QQ + q] = expf(s2sL[q] - gm) * rinv + 1.0f;
}

// -------- scale: out = in * att[lb, inner], float4-vectorized ---------------
template <int INNER>
__global__ __launch_bounds__(256) void scale_kernel(
    const float* __restrict__ in, const float* __restrict__ att,
    float* __restrict__ out, int n4)
{
    const int i = blockIdx.x * 256 + threadIdx.x;
    if (i >= n4) return;
    const float4 v = reinterpret_cast<const float4*>(in)[i];
    const float* vv = reinterpret_cast<const float*>(&v);
    float4 o;
    float* ov = reinterpret_cast<float*>(&o);
    const int g = i * 4;
#pragma unroll
    for (int j = 0; j < 4; ++j) {
        const int gg = g + j;
        const int lb = gg / (CC * INNER);
        const int x  = gg % INNER;
        ov[j] = vv[j] * att[lb * INNER + x];
    }
    reinterpret_cast<float4*>(out)[i] = o;
}

extern "C" void kernel_launch(void* const* d_in, const int* in_sizes, int n_in,
                              void* d_out, int out_size, void* d_ws, size_t ws_size,
                              hipStream_t stream)
{
    const float* zf  = (const float*)d_in[0];
    const float* xf  = (const float*)d_in[1];
    const float* W1  = (const float*)d_in[2];
    const float* b1  = (const float*)d_in[3];
    const float* g1  = (const float*)d_in[4];
    const float* bb1 = (const float*)d_in[5];
    const float* rm1 = (const float*)d_in[6];
    const float* rv1 = (const float*)d_in[7];
    const float* W2  = (const float*)d_in[8];
    const float* b2  = (const float*)d_in[9];
    const float* W3  = (const float*)d_in[10];
    const float* b3  = (const float*)d_in[11];
    const float* g3  = (const float*)d_in[12];
    const float* bb3 = (const float*)d_in[13];
    const float* rm3 = (const float*)d_in[14];
    const float* rv3 = (const float*)d_in[15];
    const float* W4  = (const float*)d_in[16];
    const float* b4  = (const float*)d_in[17];

    char* wsb = (char*)d_ws;
    unsigned short* f1T = (unsigned short*)wsb;                       // 96*64*256 us
    float* fbase = (float*)(f1T + (size_t)NLB * 64 * CC);
    float* A     = fbase;                                             // 96*49*961
    float* att1  = A + (size_t)NLB * PP * QQ;
    float* att2  = att1 + (size_t)NLB * PP;
    float* mcol  = att2 + (size_t)NLB * QQ;
    float* mrow  = mcol + (size_t)NLB * QQ;
    float* inv1  = mrow + (size_t)NLB * PP;                           // 96*64

    float* out1 = (float*)d_out;
    float* out2 = out1 + N1;

    prep_z<<<NLB, 256, 0, stream>>>(zf, f1T, inv1, mrow);

    dim3 gcorr(4, NLB);
    corr_mfma<<<gcorr, 512, 0, stream>>>(f1T, xf, inv1, A, mcol, mrow);

    attn_kernel<<<NLB, 512, 0, stream>>>(A, mcol, mrow,
        W1, b1, g1, bb1, rm1, rv1, W2, b2,
        W3, b3, g3, bb3, rm3, rv3, W4, b4,
        att1, att2);

    const int n4_1 = N1 / 4;
    const int n4_2 = N2 / 4;
    scale_kernel<PP><<<(n4_1 + 255) / 256, 256, 0, stream>>>(zf, att1, out1, n4_1);
    scale_kernel<QQ><<<(n4_2 + 255) / 256, 256, 0, stream>>>(xf, att2, out2, n4_2);
}